// Round 2
// baseline (1633.046 us; speedup 1.0000x reference)
//
#include <hip/hip_runtime.h>
#include <hip/hip_bf16.h>

// Problem constants (match reference)
#define DIMT 300      // TERM_DIM
#define DPAD 320      // padded to 32
#define NRELS 40
#define RELD 5
#define TILE_M 64     // elements per chunk/workgroup (256 threads, 4 waves)
#define MAX_CHUNKS 8192  // >= 40 + ceil(500000/64) = 7853

typedef __attribute__((ext_vector_type(8))) short bf16x8;
typedef __attribute__((ext_vector_type(4))) float f32x4;

// ---------------- workspace layout (ints) ----------------
#define DESC_OFF 256
#define SORTED_OFF (DESC_OFF + 3*MAX_CHUNKS)
#define MT_OFF_BYTES(B) ((((size_t)(SORTED_OFF + (B)) * 4) + 255) & ~(size_t)255)

__global__ void k_init(int* cnt) {
    int t = threadIdx.x;
    if (t < 64) cnt[t] = 0;
    if (t < 64) cnt[64 + t] = 0;
    if (t == 0) cnt[128] = 0;
}

__global__ void k_hist(const int* __restrict__ rels, int n, int* cnt) {
    __shared__ int l[NRELS];
    int t = threadIdx.x;
    if (t < NRELS) l[t] = 0;
    __syncthreads();
    int b = blockIdx.x * 256 + t;
    if (b < n) atomicAdd(&l[rels[b]], 1);
    __syncthreads();
    if (t < NRELS && l[t]) atomicAdd(&cnt[t], l[t]);
}

__global__ void k_scan(const int* __restrict__ cnt, int* cursor, int* n_chunks,
                       int* desc_rel, int* desc_start, int* desc_end) {
    __shared__ int offs[NRELS + 1];
    __shared__ int coff[NRELS + 1];
    if (threadIdx.x == 0) {
        int s = 0, c = 0;
        for (int r = 0; r < NRELS; r++) {
            offs[r] = s; s += cnt[r];
            coff[r] = c; c += (cnt[r] + TILE_M - 1) / TILE_M;
        }
        offs[NRELS] = s; coff[NRELS] = c;
        *n_chunks = c;
    }
    __syncthreads();
    if (threadIdx.x < NRELS) cursor[threadIdx.x] = offs[threadIdx.x];
    for (int r = 0; r < NRELS; r++) {
        int nch = (cnt[r] + TILE_M - 1) / TILE_M;
        int cend = offs[r] + cnt[r];
        for (int c = threadIdx.x; c < nch; c += 256) {
            int st = offs[r] + c * TILE_M;
            desc_rel[coff[r] + c] = r;
            desc_start[coff[r] + c] = st;
            desc_end[coff[r] + c] = min(st + TILE_M, cend);
        }
    }
}

__global__ void k_scatter(const int* __restrict__ rels, int n, int* cursor,
                          int* __restrict__ sorted) {
    __shared__ int l[NRELS];
    __shared__ int base[NRELS];
    int t = threadIdx.x;
    if (t < NRELS) l[t] = 0;
    __syncthreads();
    int b = blockIdx.x * 256 + t;
    int r = -1, loc = 0;
    if (b < n) { r = rels[b]; loc = atomicAdd(&l[r], 1); }
    __syncthreads();
    if (t < NRELS && l[t]) base[t] = atomicAdd(&cursor[t], l[t]);
    __syncthreads();
    if (b < n) sorted[base[r] + loc] = b;
}

// Mt[r][n][j] = sum_i rel_table[r,i] * assoc[i][j][n], zero-padded to 320x320.
// Linear layout (no swizzle): k_gemm reads B-fragments straight from global
// (L2-resident, 205 KB/rel), so there is no LDS and no bank to swizzle for.
__global__ void k_build_mt(const float* __restrict__ rel_table,
                           const float* __restrict__ assoc,
                           __hip_bfloat16* __restrict__ Mt) {
    int r = blockIdx.x / 100;
    int t6 = blockIdx.x % 100;
    int tn = (t6 / 10) * 32, tj = (t6 % 10) * 32;
    __shared__ float tile[32][33];
    __shared__ float rw[RELD];
    if (threadIdx.x < RELD) rw[threadIdx.x] = rel_table[r * RELD + threadIdx.x];
    __syncthreads();
    for (int e = threadIdx.x; e < 1024; e += 256) {
        int jl = e >> 5, nl = e & 31;
        int j = tj + jl, n = tn + nl;
        float v = 0.f;
        if (j < DIMT && n < DIMT) {
            #pragma unroll
            for (int i = 0; i < RELD; i++) v += rw[i] * assoc[(i * DIMT + j) * DIMT + n];
        }
        tile[jl][nl] = v;
    }
    __syncthreads();
    for (int e = threadIdx.x; e < 1024; e += 256) {
        int nl = e >> 5, jl = e & 31;
        int n = tn + nl, j = tj + jl;
        Mt[((size_t)r * DPAD + n) * DPAD + j] = __float2bfloat16(tile[jl][nl]);
    }
}

// Grouped GEMM, barrier-free: per chunk of <=64 rows of one relation:
//   X[m,n] = sum_j tL[m][j] * M[j][n]   (bf16 MFMA, fp32 acc, full 320-col X in AGPRs)
//   energy[m] = sum_n X[m,n] * tR[m,n]  (fp32 epilogue, one bursty pass)
// B-fragments are loaded DIRECTLY from global Mt each kc (no LDS staging):
// Mt's per-rel slice (205 KB) lives in L2; one bf16x8 load per (kc,nt) reads
// 16 rows x 64 contiguous bytes = 16 full lines per instruction, and all 4
// waves of a block read identical addresses so L1 (32 KB >= the 20 KB panel)
// absorbs the intra-block reuse. Zero __syncthreads -> no vmcnt(0) gang
// drains, zero LDS -> no bank conflicts; waves free-run and stagger their
// HBM gather bursts (A preload / tR epilogue) against each other's MFMAs.
__global__ __launch_bounds__(256, 3) void k_gemm(
    const int* __restrict__ sorted, const int* __restrict__ desc_rel,
    const int* __restrict__ desc_start, const int* __restrict__ desc_end,
    const int* __restrict__ n_chunks,
    const int* __restrict__ terms_L, const int* __restrict__ terms_R,
    const float* __restrict__ term_table, const __hip_bfloat16* __restrict__ Mt,
    float* __restrict__ out) {
    int cid = blockIdx.x;
    if (cid >= *n_chunks) return;
    int rel = desc_rel[cid];
    int start = desc_start[cid];
    int tm = desc_end[cid] - start;

    int t = threadIdx.x;
    int wave = t >> 6, lane = t & 63;
    int quad = lane >> 4, l16 = lane & 15;

    const __hip_bfloat16* Mtr = Mt + (size_t)rel * DPAD * DPAD;

    // ---- A preload: lane holds row sorted[start + wave*16+l16], k-octet
    // quad*8, for all 10 kc. Issued as one 20-load burst per lane so the
    // random 1.2 KB term_table row is requested in one chunky HBM burst. ----
    int arow = wave * 16 + l16;
    int ae = (arow < tm) ? sorted[start + arow] : -1;
    const float* arp = (ae >= 0) ? (term_table + (size_t)terms_L[ae] * DIMT) : nullptr;
    bf16x8 afrag[10];
    #pragma unroll
    for (int kc = 0; kc < 10; kc++) {
        int kb = kc * 32 + quad * 8;
        float v[8];
        if (arp && kb + 8 <= DIMT) {
            float4 p0 = *(const float4*)(arp + kb);
            float4 p1 = *(const float4*)(arp + kb + 4);
            v[0] = p0.x; v[1] = p0.y; v[2] = p0.z; v[3] = p0.w;
            v[4] = p1.x; v[5] = p1.y; v[6] = p1.z; v[7] = p1.w;
        } else if (arp) {
            #pragma unroll
            for (int j = 0; j < 8; j++) v[j] = (kb + j < DIMT) ? arp[kb + j] : 0.f;
        } else {
            #pragma unroll
            for (int j = 0; j < 8; j++) v[j] = 0.f;
        }
        union { bf16x8 v8; __hip_bfloat16 h[8]; } u;
        #pragma unroll
        for (int j = 0; j < 8; j++) u.h[j] = __float2bfloat16(v[j]);
        afrag[kc] = u.v8;
    }

    f32x4 acc[20];
    #pragma unroll
    for (int i = 0; i < 20; i++) acc[i] = (f32x4){0.f, 0.f, 0.f, 0.f};

    // ---- main loop: direct-from-L2 B fragments, no barriers ----
    // B-frag element = Mt[n = nt*16 + l16][ j = kc*32 + quad*8 .. +8 ]
    // byte addr = l16*640 + quad*16 + nt*10240 + kc*64
    const char* bl = (const char*)Mtr + (size_t)l16 * (DPAD * 2) + quad * 16;
    #pragma unroll
    for (int kc = 0; kc < 10; kc++) {
        const char* bk = bl + kc * 64;
        #pragma unroll
        for (int nt = 0; nt < 20; nt++) {
            bf16x8 bfrag = *(const bf16x8*)(bk + (size_t)nt * (16 * DPAD * 2));
            acc[nt] = __builtin_amdgcn_mfma_f32_16x16x32_bf16(afrag[kc], bfrag, acc[nt], 0, 0, 0);
        }
    }

    // Epilogue: lane holds X[row = wave*16 + quad*4 + reg][col = nt*16 + l16].
    // One bursty tR pass per owned row (80 independent scalar loads/lane).
    #pragma unroll
    for (int reg = 0; reg < 4; reg++) {
        int mrow = wave * 16 + quad * 4 + reg;
        int e = (mrow < tm) ? sorted[start + mrow] : -1;
        float s = 0.f;
        if (e >= 0) {
            const float* tr = term_table + (size_t)terms_R[e] * DIMT;
            #pragma unroll
            for (int nt = 0; nt < 20; nt++) {
                int n = nt * 16 + l16;
                if (n < DIMT) s += acc[nt][reg] * tr[n];
            }
        }
        s += __shfl_xor(s, 1);
        s += __shfl_xor(s, 2);
        s += __shfl_xor(s, 4);
        s += __shfl_xor(s, 8);
        if (l16 == 0 && e >= 0) out[e] = s;
    }
}

extern "C" void kernel_launch(void* const* d_in, const int* in_sizes, int n_in,
                              void* d_out, int out_size, void* d_ws, size_t ws_size,
                              hipStream_t stream) {
    const int*   rels       = (const int*)d_in[0];
    const int*   terms_L    = (const int*)d_in[1];
    const int*   terms_R    = (const int*)d_in[2];
    const float* term_table = (const float*)d_in[3];
    const float* rel_table  = (const float*)d_in[4];
    const float* assoc      = (const float*)d_in[5];
    float* out = (float*)d_out;
    int B = in_sizes[0];

    int* wsi        = (int*)d_ws;
    int* cnt        = wsi;
    int* cursor     = wsi + 64;
    int* n_chunks   = wsi + 128;
    int* desc_rel   = wsi + DESC_OFF;
    int* desc_start = desc_rel + MAX_CHUNKS;
    int* desc_end   = desc_start + MAX_CHUNKS;
    int* sorted     = wsi + SORTED_OFF;
    __hip_bfloat16* Mt = (__hip_bfloat16*)((char*)d_ws + MT_OFF_BYTES(B));

    int nb = (B + 255) / 256;
    k_init<<<1, 128, 0, stream>>>(cnt);
    k_hist<<<nb, 256, 0, stream>>>(rels, B, cnt);
    k_scan<<<1, 256, 0, stream>>>(cnt, cursor, n_chunks, desc_rel, desc_start, desc_end);
    k_scatter<<<nb, 256, 0, stream>>>(rels, B, cursor, sorted);
    k_build_mt<<<NRELS * 100, 256, 0, stream>>>(rel_table, assoc, Mt);
    k_gemm<<<MAX_CHUNKS, 256, 0, stream>>>(sorted, desc_rel, desc_start, desc_end,
                                           n_chunks, terms_L, terms_R, term_table, Mt, out);
}

// Round 3
// 1172.276 us; speedup vs baseline: 1.3931x; 1.3931x over previous
//
#include <hip/hip_runtime.h>
#include <hip/hip_bf16.h>
#include <hip/hip_fp16.h>

// Problem constants (match reference)
#define DIMT 300      // TERM_DIM
#define DPAD 320      // padded to 32
#define NRELS 40
#define RELD 5
#define TILE_M 64     // rows per chunk/workgroup (256 threads, 4 waves x 16 rows)
#define MAX_CHUNKS 8192  // >= 40 + ceil(500000/64) = 7853

#define PROWS 16              // n-rows per staged panel
#define NPANELS 20            // 320 / 16
#define PBYTES (PROWS * DPAD * 2)   // 10240 B per panel

typedef __attribute__((ext_vector_type(8))) short bf16x8;
typedef __attribute__((ext_vector_type(4))) float f32x4;

// ---------------- workspace layout (ints) ----------------
#define DESC_OFF 256
#define SORTED_OFF (DESC_OFF + 3*MAX_CHUNKS)
#define MT_OFF_BYTES(B) ((((size_t)(SORTED_OFF + (B)) * 4) + 255) & ~(size_t)255)

__global__ void k_init(int* cnt) {
    int t = threadIdx.x;
    if (t < 64) cnt[t] = 0;
    if (t < 64) cnt[64 + t] = 0;
    if (t == 0) cnt[128] = 0;
}

__global__ void k_hist(const int* __restrict__ rels, int n, int* cnt) {
    __shared__ int l[NRELS];
    int t = threadIdx.x;
    if (t < NRELS) l[t] = 0;
    __syncthreads();
    int b = blockIdx.x * 256 + t;
    if (b < n) atomicAdd(&l[rels[b]], 1);
    __syncthreads();
    if (t < NRELS && l[t]) atomicAdd(&cnt[t], l[t]);
}

__global__ void k_scan(const int* __restrict__ cnt, int* cursor, int* n_chunks,
                       int* desc_rel, int* desc_start, int* desc_end) {
    __shared__ int offs[NRELS + 1];
    __shared__ int coff[NRELS + 1];
    if (threadIdx.x == 0) {
        int s = 0, c = 0;
        for (int r = 0; r < NRELS; r++) {
            offs[r] = s; s += cnt[r];
            coff[r] = c; c += (cnt[r] + TILE_M - 1) / TILE_M;
        }
        offs[NRELS] = s; coff[NRELS] = c;
        *n_chunks = c;
    }
    __syncthreads();
    if (threadIdx.x < NRELS) cursor[threadIdx.x] = offs[threadIdx.x];
    for (int r = 0; r < NRELS; r++) {
        int nch = (cnt[r] + TILE_M - 1) / TILE_M;
        int cend = offs[r] + cnt[r];
        for (int c = threadIdx.x; c < nch; c += 256) {
            int st = offs[r] + c * TILE_M;
            desc_rel[coff[r] + c] = r;
            desc_start[coff[r] + c] = st;
            desc_end[coff[r] + c] = min(st + TILE_M, cend);
        }
    }
}

__global__ void k_scatter(const int* __restrict__ rels, int n, int* cursor,
                          int* __restrict__ sorted) {
    __shared__ int l[NRELS];
    __shared__ int base[NRELS];
    int t = threadIdx.x;
    if (t < NRELS) l[t] = 0;
    __syncthreads();
    int b = blockIdx.x * 256 + t;
    int r = -1, loc = 0;
    if (b < n) { r = rels[b]; loc = atomicAdd(&l[r], 1); }
    __syncthreads();
    if (t < NRELS && l[t]) base[t] = atomicAdd(&cursor[t], l[t]);
    __syncthreads();
    if (b < n) sorted[base[r] + loc] = b;
}

// Mt[r][n][.] = sum_i rel_table[r,i] * assoc[i][j][n], zero-padded to 320x320,
// with the j dimension stored XOR-swizzled per row: 8-element j-chunk jc lands
// at chunk position (jc ^ (n & 7)). k_gemm stages panels with a LINEAR
// global_load_lds copy (swizzle pre-baked in global memory) and applies the
// matching XOR on the ds_read side -> zero bank conflicts (R1-verified).
__global__ void k_build_mt(const float* __restrict__ rel_table,
                           const float* __restrict__ assoc,
                           __hip_bfloat16* __restrict__ Mt) {
    int r = blockIdx.x / 100;
    int t6 = blockIdx.x % 100;
    int tn = (t6 / 10) * 32, tj = (t6 % 10) * 32;
    __shared__ float tile[32][33];
    __shared__ float rw[RELD];
    if (threadIdx.x < RELD) rw[threadIdx.x] = rel_table[r * RELD + threadIdx.x];
    __syncthreads();
    for (int e = threadIdx.x; e < 1024; e += 256) {
        int jl = e >> 5, nl = e & 31;
        int j = tj + jl, n = tn + nl;
        float v = 0.f;
        if (j < DIMT && n < DIMT) {
            #pragma unroll
            for (int i = 0; i < RELD; i++) v += rw[i] * assoc[(i * DIMT + j) * DIMT + n];
        }
        tile[jl][nl] = v;
    }
    __syncthreads();
    for (int e = threadIdx.x; e < 1024; e += 256) {
        int nl = e >> 5, jl = e & 31;
        int n = tn + nl, j = tj + jl;
        int sj = (((j >> 3) ^ (n & 7)) << 3) | (j & 7);   // XOR-swizzled j position
        Mt[((size_t)r * DPAD + n) * DPAD + sj] = __float2bfloat16(tile[jl][nl]);
    }
}

// async 4B global -> LDS (direct-to-shared DMA); width 4 gives a uniform
// 10 dwords/thread per 10 KB panel (no ragged chunk assignment, so vmcnt
// bookkeeping is wave-uniform).
__device__ inline void async_g2l4(const void* g, void* l) {
    __builtin_amdgcn_global_load_lds(
        (const __attribute__((address_space(1))) unsigned int*)g,
        (__attribute__((address_space(3))) unsigned int*)l, 4, 0, 0);
}

// Grouped GEMM, swapped-operand MFMA + N-panel-outer + counted-vmcnt pipeline.
// Per chunk of <=64 rows of one relation:
//   mfma(bfrag, afrag, acc) computes X^T: lane (quad,l16) owns output row
//   m = wave*16+l16 (same row for A-gather, tR-gather and the output!) and
//   cols n = panel*16 + quad*4 + reg.
// Per 16-col panel: 10 MFMAs into an 8-reg acc, immediately contracted with
// register-resident fp16-packed tR. Panels triple-buffered in LDS (3x10KB),
// staged 2 ahead via global_load_lds; one raw s_barrier per phase with
// s_waitcnt vmcnt(10) -- the in-flight stage is never drained to 0 mid-loop.
__global__ __launch_bounds__(256, 4) void k_gemm(
    const int* __restrict__ sorted, const int* __restrict__ desc_rel,
    const int* __restrict__ desc_start, const int* __restrict__ desc_end,
    const int* __restrict__ n_chunks,
    const int* __restrict__ terms_L, const int* __restrict__ terms_R,
    const float* __restrict__ term_table, const __hip_bfloat16* __restrict__ Mt,
    float* __restrict__ out) {
    int cid = blockIdx.x;
    if (cid >= *n_chunks) return;
    int rel = desc_rel[cid];
    int start = desc_start[cid];
    int tm = desc_end[cid] - start;

    __shared__ __align__(16) char Blds[3][PBYTES];   // 30720 B total

    int t = threadIdx.x;
    int wave = t >> 6, lane = t & 63;
    int quad = lane >> 4, l16 = lane & 15;

    const char* Mtb = (const char*)(Mt + (size_t)rel * DPAD * DPAD);

    // ---- panel staging: 10 KB = 2560 dwords, 10 per thread, fully linear ----
    auto stage = [&](int np, int buf) {
        const char* gb = Mtb + (size_t)np * PBYTES;
        char* lb = &Blds[buf][0];
        #pragma unroll
        for (int i = 0; i < 10; i++) {
            int d4 = (t + i * 256) * 4;
            async_g2l4(gb + d4, lb + d4);
        }
    };

    // kick off the first two panel DMAs before the long gather chain
    stage(0, 0);
    stage(1, 1);

    // ---- row identity: ONE row per lane (shared by all 4 quads via l16) ----
    int mrow = wave * 16 + l16;
    int e = (mrow < tm) ? sorted[start + mrow] : -1;
    const float* arp = term_table + (size_t)((e >= 0) ? terms_L[e] : 0) * DIMT;
    const float* trp = term_table + (size_t)((e >= 0) ? terms_R[e] : 0) * DIMT;

    // ---- A preload: lane holds tL[m][kc*32 + quad*8 .. +8] for all 10 kc ----
    bf16x8 afrag[10];
    #pragma unroll
    for (int kc = 0; kc < 10; kc++) {
        int kb = kc * 32 + quad * 8;
        float v[8];
        if (e >= 0 && kb + 8 <= DIMT) {
            float4 p0 = *(const float4*)(arp + kb);
            float4 p1 = *(const float4*)(arp + kb + 4);
            v[0] = p0.x; v[1] = p0.y; v[2] = p0.z; v[3] = p0.w;
            v[4] = p1.x; v[5] = p1.y; v[6] = p1.z; v[7] = p1.w;
        } else if (e >= 0) {
            #pragma unroll
            for (int j = 0; j < 8; j++) v[j] = (kb + j < DIMT) ? arp[kb + j] : 0.f;
        } else {
            #pragma unroll
            for (int j = 0; j < 8; j++) v[j] = 0.f;
        }
        union { bf16x8 v8; __hip_bfloat16 h[8]; } u;
        #pragma unroll
        for (int j = 0; j < 8; j++) u.h[j] = __float2bfloat16(v[j]);
        afrag[kc] = u.v8;
    }

    // ---- tR preload: per panel this lane needs tr[m][np*16 + quad*4 .. +4].
    // One float4 per panel, packed to 2x half2 (40 VGPR total). Column base
    // clamped to 296 for the padded tail: those acc lanes are exactly 0
    // (Mt rows >= 300 are zero), so junk-but-finite tR values contribute 0.
    __half2 trh[NPANELS * 2];
    #pragma unroll
    for (int np = 0; np < NPANELS; np++) {
        int cb = np * 16 + quad * 4;
        if (cb > 296) cb = 296;
        float4 v = *(const float4*)(trp + cb);
        trh[np * 2 + 0] = __halves2half2(__float2half(v.x), __float2half(v.y));
        trh[np * 2 + 1] = __halves2half2(__float2half(v.z), __float2half(v.w));
    }

    // Drain everything (gathers consumed above; stage(0)/stage(1) landed).
    // Establishes the loop invariant: outstanding vmem = issued in-loop stages.
    asm volatile("s_waitcnt vmcnt(0)" ::: "memory");

    int sw3 = l16 & 7;
    float en = 0.f;

    #pragma unroll
    for (int p = 0; p < NPANELS; p++) {
        __builtin_amdgcn_sched_barrier(0);   // keep prev phase's MFMAs above the wait
        if (p < NPANELS - 1) {
            asm volatile("s_waitcnt vmcnt(10)" ::: "memory");  // stage(p) landed; stage(p+1) in flight
        } else {
            asm volatile("s_waitcnt vmcnt(0)" ::: "memory");   // last panel: drain
        }
        __builtin_amdgcn_s_barrier();        // all waves' stage(p) chunks are in LDS
        __builtin_amdgcn_sched_barrier(0);   // no ds_read hoisting above the barrier
        if (p + 2 < NPANELS) stage(p + 2, (p + 2) % 3);  // buf last read in phase p-1

        const char* bb = &Blds[p % 3][0] + l16 * (DPAD * 2);
        f32x4 acc0 = {0.f, 0.f, 0.f, 0.f};
        f32x4 acc1 = {0.f, 0.f, 0.f, 0.f};
        #pragma unroll
        for (int kc = 0; kc < 10; kc += 2) {
            bf16x8 b0 = *(const bf16x8*)(bb + ((((kc    ) * 4 + quad) ^ sw3) << 4));
            bf16x8 b1 = *(const bf16x8*)(bb + ((((kc + 1) * 4 + quad) ^ sw3) << 4));
            acc0 = __builtin_amdgcn_mfma_f32_16x16x32_bf16(b0, afrag[kc],     acc0, 0, 0, 0);
            acc1 = __builtin_amdgcn_mfma_f32_16x16x32_bf16(b1, afrag[kc + 1], acc1, 0, 0, 0);
        }
        // contract this panel with register-resident tR
        float2 f01 = __half22float2(trh[p * 2 + 0]);
        float2 f23 = __half22float2(trh[p * 2 + 1]);
        en += (acc0[0] + acc1[0]) * f01.x + (acc0[1] + acc1[1]) * f01.y
            + (acc0[2] + acc1[2]) * f23.x + (acc0[3] + acc1[3]) * f23.y;
    }

    // Reduce over the 4 quads (lane bits 4,5) -> full row sum; quad 0 writes.
    float s = en;
    s += __shfl_xor(s, 16);
    s += __shfl_xor(s, 32);
    if (quad == 0 && e >= 0) out[e] = s;
}

extern "C" void kernel_launch(void* const* d_in, const int* in_sizes, int n_in,
                              void* d_out, int out_size, void* d_ws, size_t ws_size,
                              hipStream_t stream) {
    const int*   rels       = (const int*)d_in[0];
    const int*   terms_L    = (const int*)d_in[1];
    const int*   terms_R    = (const int*)d_in[2];
    const float* term_table = (const float*)d_in[3];
    const float* rel_table  = (const float*)d_in[4];
    const float* assoc      = (const float*)d_in[5];
    float* out = (float*)d_out;
    int B = in_sizes[0];

    int* wsi        = (int*)d_ws;
    int* cnt        = wsi;
    int* cursor     = wsi + 64;
    int* n_chunks   = wsi + 128;
    int* desc_rel   = wsi + DESC_OFF;
    int* desc_start = desc_rel + MAX_CHUNKS;
    int* desc_end   = desc_start + MAX_CHUNKS;
    int* sorted     = wsi + SORTED_OFF;
    __hip_bfloat16* Mt = (__hip_bfloat16*)((char*)d_ws + MT_OFF_BYTES(B));

    int nb = (B + 255) / 256;
    k_init<<<1, 128, 0, stream>>>(cnt);
    k_hist<<<nb, 256, 0, stream>>>(rels, B, cnt);
    k_scan<<<1, 256, 0, stream>>>(cnt, cursor, n_chunks, desc_rel, desc_start, desc_end);
    k_scatter<<<nb, 256, 0, stream>>>(rels, B, cursor, sorted);
    k_build_mt<<<NRELS * 100, 256, 0, stream>>>(rel_table, assoc, Mt);
    k_gemm<<<MAX_CHUNKS, 256, 0, stream>>>(sorted, desc_rel, desc_start, desc_end,
                                           n_chunks, terms_L, terms_R, term_table, Mt, out);
}